// Round 13
// baseline (33.544 us; speedup 1.0000x reference)
//
#include <hip/hip_runtime.h>

#define IN_SIZE 11
#define HID 16
#define FEAT 18
#define TSTEPS 18
#define CAP 1024     // LDS worklist capacity (this input: ~4-15 entries/block)
#define SWEEPS 8     // int4 sweeps per thread -> 32 elements/thread

__device__ __forceinline__ float fast_rcp(float v) { return __builtin_amdgcn_rcpf(v); }

// broadcast a float from a fixed lane via v_readlane (SGPR path, no DS)
__device__ __forceinline__ float rl(float v, int lane) {
    return __int_as_float(__builtin_amdgcn_readlane(__float_as_int(v), lane));
}

// Single kernel, block-local two phases (no grid sync anywhere):
//   Phase 1 (detect, WAVE-COALESCED): block owns 8192 elements of sorted
//     batch[]. Sweep s: lane reads int4 #(s*256+tid) -> consecutive lanes,
//     consecutive 16B (1 KB/wave/instr). All 8 loads issued before use.
//     Rise batch[j] > batch[j-1] => first[v]=j; push (v,j) to LDS list;
//     value gaps and the tail above batch[E-1] push (v,-1) = empty graph.
//     Each graph is discovered by exactly one thread grid-wide.
//   Phase 2 (process): the block's 4 waves loop over the list; per graph:
//     cnt = run-length of g at j (ballot over contiguous batch[j..j+17]),
//     edge fetch, x gather, readlane LSTM, fc. (r12-validated body.)
extern "C" __global__ __launch_bounds__(256, 4)
void tgnn_rise_lstm(const float* __restrict__ x,
                    const float* __restrict__ W_ih,
                    const float* __restrict__ W_hh,
                    const float* __restrict__ b_ih,
                    const float* __restrict__ b_hh,
                    const float* __restrict__ W_fc,
                    const float* __restrict__ b_fc,
                    const int* __restrict__ edge_index,
                    const int* __restrict__ edge_attr,
                    const int* __restrict__ batch,
                    float* __restrict__ out,
                    int E, int B)
{
    __shared__ int lcnt;
    __shared__ int lg[CAP];
    __shared__ int lj[CAP];

    if (threadIdx.x == 0) lcnt = 0;
    __syncthreads();

    auto push = [&](int g2, int j) {
        const int slot = atomicAdd(&lcnt, 1);
        if (slot < CAP) { lg[slot] = g2; lj[slot] = j; }
    };

    const int wl = threadIdx.x & 63;

    // ---------------- Phase 1: wave-coalesced rise detection ----------------
    {
        const int4* b4 = reinterpret_cast<const int4*>(batch);
        const int span4 = blockDim.x * SWEEPS;             // int4s per block
        const int base4 = blockIdx.x * span4;

        int4 q[SWEEPS];
        int  e0[SWEEPS];
        // issue all sweep loads first (independent; one latency round)
#pragma unroll
        for (int s = 0; s < SWEEPS; ++s) {
            const int i4 = base4 + s * (int)blockDim.x + (int)threadIdx.x;
            e0[s] = i4 * 4;
            if (e0[s] + 4 <= E) {
                q[s] = b4[i4];                             // coalesced 16B/lane
            } else if (e0[s] < E) {                        // partial last int4
                int last = batch[e0[s]];
                int vv[4];
                vv[0] = last;
#pragma unroll
                for (int t2 = 1; t2 < 4; ++t2) {
                    if (e0[s] + t2 < E) last = batch[e0[s] + t2];
                    vv[t2] = last;                         // repeat => no rise
                }
                q[s] = make_int4(vv[0], vv[1], vv[2], vv[3]);
            } else {
                q[s] = make_int4(0, 0, 0, 0);              // fully OOB
            }
        }
        // process sweeps
#pragma unroll
        for (int s = 0; s < SWEEPS; ++s) {
            const int pw = __shfl_up(q[s].w, 1, 64);       // lane l-1's last elem
            if (e0[s] < E) {
                int prev;
                if (wl == 0) prev = (e0[s] == 0) ? -1 : batch[e0[s] - 1];
                else         prev = pw;
                const int va[5] = {prev, q[s].x, q[s].y, q[s].z, q[s].w};
                if (va[4] > va[0]) {                       // rare: rise here
#pragma unroll
                    for (int t2 = 1; t2 <= 4; ++t2) {
                        if (va[t2] > va[t2 - 1]) {
                            const int j = e0[s] + t2 - 1;
                            for (int g2 = va[t2 - 1] + 1; g2 <= va[t2]; ++g2)
                                push(g2, (g2 == va[t2]) ? j : -1);
                        }
                    }
                }
                if (e0[s] <= E - 1 && E - 1 < e0[s] + 4) { // owns last element
                    const int lastv = va[(E - 1 - e0[s]) + 1];
                    for (int g2 = lastv + 1; g2 < B; ++g2) push(g2, -1);
                }
            }
        }
    }
    __syncthreads();                                       // block-local only
    const int n = (lcnt < CAP) ? lcnt : CAP;

    // ---------------- Phase 2: per-wave LSTM over discovered graphs ---------
    const int wid = threadIdx.x >> 6;
    const int u   = wl & 15;
    const int r   = wl >> 4;
    const int row = wl;

    if (n == 0) return;

    // per-lane weights (loaded once; L2-hot after the first blocks)
    float wih[IN_SIZE], whh[HID];
#pragma unroll
    for (int k = 0; k < IN_SIZE; ++k) wih[k] = W_ih[row * FEAT + k];
#pragma unroll
    for (int v = 0; v < HID; ++v) whh[v] = W_hh[row * HID + v];
    const float bias = b_ih[row] + b_hh[row];
    const float wfc  = W_fc[row];
    const float bfc  = b_fc[r];

    const float sa = (r == 2) ? -2.0f : -1.0f;   // own-gate act: r==2 -> tanh
    const float ma = (r == 2) ?  2.0f :  1.0f;
    const float oa = (r == 2) ? -1.0f :  0.0f;

    for (int e = wid; e < n; e += 4) {
        const int g2   = lg[e];
        const int jraw = lj[e];
        const int j    = (jraw < 0) ? 0 : jraw;

        // batch-run + edge fetch: lanes 0..17, contiguous rows (one round)
        int bj = -1, n1 = 0, n2 = 0, ea = 0;
        if (wl < TSTEPS) {
            const int idx  = j + wl;
            const int cidx = (idx > E - 1) ? E - 1 : idx;
            bj = (idx < E) ? batch[cidx] : -1;
            n1 = edge_index[cidx];
            n2 = edge_index[E + cidx];
            ea = edge_attr[cidx];            // in [0,7) even when clamped
        }
        const unsigned long long mask = __ballot(bj == g2);
        int cnt = (jraw < 0) ? 0 : (int)__builtin_ctzll(~mask);  // run length
        if (cnt > TSTEPS) cnt = TSTEPS;

        // x gather: lane t holds step t's 11 summed features (one round)
        float f[IN_SIZE];
        {
            const float* xa = x + (long)n1 * IN_SIZE;
            const float* xb = x + (long)n2 * IN_SIZE;
#pragma unroll
            for (int k = 0; k < IN_SIZE; ++k) f[k] = xa[k] + xb[k];
        }
        if (wl >= cnt) {
#pragma unroll
            for (int k = 0; k < IN_SIZE; ++k) f[k] = 0.0f;
        }

        // prologue: a_in[t] = bias + x_t . wih_row + onehot-weight
        float ain[TSTEPS];
#pragma unroll
        for (int t = 0; t < TSTEPS; ++t) {
            const int eat = __builtin_amdgcn_readlane(ea, t);   // uniform
            const float w1 = W_ih[row * FEAT + IN_SIZE + eat];  // L1-hot
            float a = bias + ((t < cnt) ? w1 : 0.0f);
#pragma unroll
            for (int k = 0; k < IN_SIZE; ++k)
                a = fmaf(rl(f[k], t), wih[k], a);
            ain[t] = a;
        }

        // LSTM: 16 readlane + 16 FMA + 1 own-gate act + 3 swizzles per step
        float h = 0.0f, c = 0.0f;
#pragma unroll
        for (int t = 0; t < TSTEPS; ++t) {
            float a;
            if (t == 0) {
                a = ain[0];
            } else {
                float A0 = ain[t], A1 = 0.0f, A2 = 0.0f, A3 = 0.0f;
#pragma unroll
                for (int v = 0; v < HID; v += 4) {
                    A0 = fmaf(rl(h, v + 0), whh[v + 0], A0);
                    A1 = fmaf(rl(h, v + 1), whh[v + 1], A1);
                    A2 = fmaf(rl(h, v + 2), whh[v + 2], A2);
                    A3 = fmaf(rl(h, v + 3), whh[v + 3], A3);
                }
                a = (A0 + A1) + (A2 + A3);
            }
            const float act = fmaf(ma, fast_rcp(1.0f + __expf(sa * a)), oa);
            const float s1 = __shfl_xor(act, 16, 64);   // sigma(f)
            const float s2 = __shfl_xor(act, 32, 64);   // tanh(g)
            const float s3 = __shfl_xor(s1, 32, 64);    // sigma(o)
            c = fmaf(s1, c, act * s2);                  // lanes 0..15 valid
            const float th = fmaf(2.0f, fast_rcp(1.0f + __expf(-2.0f * c)), -1.0f);
            h = s3 * th;
        }

        // fc epilogue
        const float hb = __shfl(h, u, 64);
        float p = hb * wfc;
#pragma unroll
        for (int m = 8; m >= 1; m >>= 1) p += __shfl_xor(p, m, 16);
        if (u == 0) out[g2 * 4 + r] = p + bfc;
    }
}

extern "C" void kernel_launch(void* const* d_in, const int* in_sizes, int n_in,
                              void* d_out, int out_size, void* d_ws, size_t ws_size,
                              hipStream_t stream) {
    const float* x     = (const float*)d_in[0];
    const float* W_ih  = (const float*)d_in[1];
    const float* W_hh  = (const float*)d_in[2];
    const float* b_ih  = (const float*)d_in[3];
    const float* b_hh  = (const float*)d_in[4];
    const float* W_fc  = (const float*)d_in[5];
    const float* b_fc  = (const float*)d_in[6];
    const int* edge_index = (const int*)d_in[7];
    const int* edge_attr  = (const int*)d_in[8];
    const int* batch      = (const int*)d_in[9];

    const int E = in_sizes[8];            // N_EDGES
    const int B = out_size / 4;           // N_GRAPHS

    const int span = 256 * 32;            // elements per block
    const int grid = (E + span - 1) / span;   // 977 blocks for E=8M

    tgnn_rise_lstm<<<grid, 256, 0, stream>>>(x, W_ih, W_hh, b_ih, b_hh,
                                             W_fc, b_fc,
                                             edge_index, edge_attr, batch,
                                             (float*)d_out, E, B);
}

// Round 14
// 25.773 us; speedup vs baseline: 1.3015x; 1.3015x over previous
//
#include <hip/hip_runtime.h>

#define IN_SIZE 11
#define HID 16
#define FEAT 18
#define TSTEPS 18

__device__ __forceinline__ float fast_rcp(float v) { return __builtin_amdgcn_rcpf(v); }

// broadcast a float from a fixed lane via v_readlane (SGPR path, no DS)
__device__ __forceinline__ float rl(float v, int lane) {
    return __int_as_float(__builtin_amdgcn_readlane(__float_as_int(v), lane));
}

// One WAVE per graph. Lane wl owns gate row wl (r=wl>>4, u=wl&15).
// Search: SINGLE-target 64-ary lower_bound(batch, g) by the whole wave:
//   - round-1 probes ((E*wl)>>6) are input-constant -> issued at kernel entry
//     with the weight loads (latency shared with the mandatory initial round)
//   - 2 more wide rounds (125K -> 1953 -> ~31) + contiguous <=64-elem final
//   - cnt = run-length of g at f0 via ballot over batch[f0..f0+17], riding
//     the edge-fetch round (those lines are L1-hot from the final scan)
// Dependent memory rounds after entry: R2, R3, final, edges, x  (r6 had 7).
// Gather + readlane LSTM body identical to r6 (validated).
extern "C" __global__ __launch_bounds__(256, 4)
void tgnn_lstm_fused(const float* __restrict__ x,
                     const float* __restrict__ W_ih,
                     const float* __restrict__ W_hh,
                     const float* __restrict__ b_ih,
                     const float* __restrict__ b_hh,
                     const float* __restrict__ W_fc,
                     const float* __restrict__ b_fc,
                     const int* __restrict__ edge_index,
                     const int* __restrict__ edge_attr,
                     const int* __restrict__ batch,
                     float* __restrict__ out,
                     int E, int B)
{
    const int wl  = threadIdx.x & 63;
    const int g   = (blockIdx.x * blockDim.x + threadIdx.x) >> 6;  // wave = graph
    const int u   = wl & 15;
    const int r   = wl >> 4;
    const int row = wl;
    const int vt  = g;                   // wave-uniform search target

    // ---- round-1 probe (input-constant address) issued FIRST ----
    const int p1 = (int)(((unsigned)E * (unsigned)wl) >> 6);   // < E
    const int b1 = batch[p1];

    // ---- per-lane weights: issued behind the R1 probes, same latency round ----
    float wih[IN_SIZE], whh[HID];
#pragma unroll
    for (int k = 0; k < IN_SIZE; ++k) wih[k] = W_ih[row * FEAT + k];
#pragma unroll
    for (int v = 0; v < HID; ++v) whh[v] = W_hh[row * HID + v];
    const float bias = b_ih[row] + b_hh[row];
    const float wfc  = W_fc[row];
    const float bfc  = b_fc[r];

    // ---- resolve round 1 (ballot prefix; sorted => "< vt" is a lane prefix) ----
    int lo, hi;
    {
        const unsigned c = (unsigned)__popcll(__ballot(b1 < vt));
        lo = c ? (int)(((unsigned)E * (c - 1)) >> 6) + 1 : 0;
        hi = (c < 64u) ? (int)(((unsigned)E * c) >> 6) : E;
    }
    int n = hi - lo;
    // ---- wide rounds (64 probes each) until window fits one contiguous scan ----
    while (n > 64) {
        const int p  = lo + (int)(((unsigned)n * (unsigned)wl) >> 6);   // < hi
        const int bv = batch[p];
        const unsigned c = (unsigned)__popcll(__ballot(bv < vt));
        const int nlo = c ? (lo + (int)(((unsigned)n * (c - 1)) >> 6) + 1) : lo;
        const int nhi = (c < 64u) ? (lo + (int)(((unsigned)n * c) >> 6)) : hi;
        lo = nlo; hi = nhi; n = hi - lo;
    }
    {   // final: contiguous scan of [lo, lo+n), n <= 64 (2-4 fully-used lines)
        int p = lo + wl; if (p > E - 1) p = E - 1;
        const bool lt = (wl < n) && (batch[p] < vt);
        lo += (int)__popcll(__ballot(lt));
    }
    const int f0 = lo;                   // lower_bound(batch, g), wave-uniform

    // ---- edge fetch + batch-run (lanes 0..17, contiguous; batch L1-hot) ----
    int bj = -1, n1 = 0, n2 = 0, ea = 0;
    if (wl < TSTEPS) {
        const int idx  = f0 + wl;
        const int cidx = (idx > E - 1) ? E - 1 : idx;
        bj = (idx < E) ? batch[cidx] : -1;
        n1 = edge_index[cidx];
        n2 = edge_index[E + cidx];
        ea = edge_attr[cidx];            // in [0,7) even when clamped
    }
    const unsigned long long mask = __ballot(bj == vt);
    int cnt = (int)__builtin_ctzll(~mask);          // run length of g at f0
    if (cnt > TSTEPS) cnt = TSTEPS;

    // ---- x gather: lane t holds step t's 11 summed features (one round) ----
    float f[IN_SIZE];
    {
        const float* xa = x + (long)n1 * IN_SIZE;
        const float* xb = x + (long)n2 * IN_SIZE;
#pragma unroll
        for (int k = 0; k < IN_SIZE; ++k) f[k] = xa[k] + xb[k];
    }
    if (wl >= cnt) {                     // invalid steps AND lanes >= 18
#pragma unroll
        for (int k = 0; k < IN_SIZE; ++k) f[k] = 0.0f;
    }

    // ---- prologue: a_in[t] = bias + x_t . wih_row + onehot-weight (per lane) ----
    float ain[TSTEPS];
#pragma unroll
    for (int t = 0; t < TSTEPS; ++t) {
        const int eat = __builtin_amdgcn_readlane(ea, t);   // uniform
        const float w1 = W_ih[row * FEAT + IN_SIZE + eat];  // L1-hot (4.6 KB)
        float a = bias + ((t < cnt) ? w1 : 0.0f);
#pragma unroll
        for (int k = 0; k < IN_SIZE; ++k)
            a = fmaf(rl(f[k], t), wih[k], a);
        ain[t] = a;
    }

    // ---- LSTM: per step 16 readlane + 16 FMA + 1 own-gate act + 3 swizzles ----
    const float sa = (r == 2) ? -2.0f : -1.0f;   // r==2 -> tanh via 2*sig(2a)-1
    const float ma = (r == 2) ?  2.0f :  1.0f;
    const float oa = (r == 2) ? -1.0f :  0.0f;

    float h = 0.0f, c = 0.0f;
#pragma unroll
    for (int t = 0; t < TSTEPS; ++t) {
        float a;
        if (t == 0) {
            a = ain[0];
        } else {
            float A0 = ain[t], A1 = 0.0f, A2 = 0.0f, A3 = 0.0f;
#pragma unroll
            for (int v = 0; v < HID; v += 4) {
                A0 = fmaf(rl(h, v + 0), whh[v + 0], A0);
                A1 = fmaf(rl(h, v + 1), whh[v + 1], A1);
                A2 = fmaf(rl(h, v + 2), whh[v + 2], A2);
                A3 = fmaf(rl(h, v + 3), whh[v + 3], A3);
            }
            a = (A0 + A1) + (A2 + A3);
        }
        const float act = fmaf(ma, fast_rcp(1.0f + __expf(sa * a)), oa);
        const float s1 = __shfl_xor(act, 16, 64);   // sigma(f)
        const float s2 = __shfl_xor(act, 32, 64);   // tanh(g)
        const float s3 = __shfl_xor(s1, 32, 64);    // sigma(o)
        c = fmaf(s1, c, act * s2);                  // lanes 0..15 valid
        const float th = fmaf(2.0f, fast_rcp(1.0f + __expf(-2.0f * c)), -1.0f);
        h = s3 * th;
    }

    // ---- fc epilogue ----
    const float hb = __shfl(h, u, 64);              // lane wl <- h[u] from lane u
    float p = hb * wfc;                             // W_fc[r][u] == W_fc[row]
#pragma unroll
    for (int m = 8; m >= 1; m >>= 1) p += __shfl_xor(p, m, 16);
    if (u == 0 && g < B) out[g * 4 + r] = p + bfc;
}

extern "C" void kernel_launch(void* const* d_in, const int* in_sizes, int n_in,
                              void* d_out, int out_size, void* d_ws, size_t ws_size,
                              hipStream_t stream) {
    const float* x     = (const float*)d_in[0];
    const float* W_ih  = (const float*)d_in[1];
    const float* W_hh  = (const float*)d_in[2];
    const float* b_ih  = (const float*)d_in[3];
    const float* b_hh  = (const float*)d_in[4];
    const float* W_fc  = (const float*)d_in[5];
    const float* b_fc  = (const float*)d_in[6];
    const int* edge_index = (const int*)d_in[7];
    const int* edge_attr  = (const int*)d_in[8];
    const int* batch      = (const int*)d_in[9];

    const int E = in_sizes[8];       // N_EDGES
    const int B = out_size / 4;      // N_GRAPHS

    const int grid = (B + 3) / 4;    // 4 graphs (waves) per 256-thread block
    tgnn_lstm_fused<<<grid, 256, 0, stream>>>(x, W_ih, W_hh, b_ih, b_hh,
                                              W_fc, b_fc,
                                              edge_index, edge_attr, batch,
                                              (float*)d_out, E, B);
}